// Round 1
// baseline (8967.596 us; speedup 1.0000x reference)
//
#include <hip/hip_runtime.h>
#include <math.h>

namespace {
constexpr int CC  = 512;    // channels
constexpr int NN  = 4096;   // H*W
constexpr int JT  = 32;     // query-column tile per workgroup
constexpr int IB  = 64;     // key block per iteration
constexpr int TPB = 256;    // threads per block
constexpr int NJT = NN / JT;   // 128 j-tiles per batch
}

__global__ __launch_bounds__(TPB, 2)
void attn_fused_f32(const float* __restrict__ Q,
                    const float* __restrict__ K,
                    const float* __restrict__ V,
                    float* __restrict__ O)
{
    // LDS: 64 KB Q-tile + 8.5 KB transposed P + 2 KB reductions = ~74.7 KB
    __shared__ float q_lds[CC][JT];
    __shared__ float p_t[JT][IB + 4];    // padded row (68 f32) to spread banks
    __shared__ float red_max[8][JT];
    __shared__ float red_sum[8][JT];

    const int t  = (int)threadIdx.x;
    const int j  = t & (JT - 1);   // column within tile (0..31)
    const int g  = t >> 5;         // group 0..7: i-range for S, c-range for out
    const int b  = (int)blockIdx.x / NJT;
    const int j0 = ((int)blockIdx.x % NJT) * JT;

    const float* __restrict__ Qb = Q + ((size_t)b * CC) * NN + j0;
    const float* __restrict__ Kb = K + ((size_t)b * CC) * NN;
    const float* __restrict__ Vb = V + ((size_t)b * CC) * NN;
    float* __restrict__       Ob = O + ((size_t)b * CC) * NN + j0;

    // ---- stage Q tile [512 c][32 j] into LDS (read once per WG) ----
    #pragma unroll 4
    for (int r = 0; r < (CC * JT) / TPB; ++r) {
        int idx = r * TPB + t;
        int c   = idx >> 5;
        int jj  = idx & (JT - 1);
        q_lds[c][jj] = Qb[(size_t)c * NN + jj];
    }
    __syncthreads();

    // per-thread output accumulator: column j, channels c = g*64 .. g*64+63
    float acc[64];
    #pragma unroll
    for (int x = 0; x < 64; ++x) acc[x] = 0.0f;
    float m_run = -INFINITY;
    float l_run = 0.0f;

    for (int i0 = 0; i0 < NN; i0 += IB) {
        // ================= Phase A: S-block =================
        // s_acc[r] = sum_c K[c][i0 + g*8 + r] * Q[c][j0 + j]
        float s_acc[8];
        #pragma unroll
        for (int r = 0; r < 8; ++r) s_acc[r] = 0.0f;

        const float* kp = Kb + i0 + g * 8;   // wave-uniform-ish base
        #pragma unroll 4
        for (int c = 0; c < CC; ++c) {
            float qv = q_lds[c][j];
            const float4 k0 = *(const float4*)(kp + (size_t)c * NN);
            const float4 k1 = *(const float4*)(kp + (size_t)c * NN + 4);
            s_acc[0] = fmaf(k0.x, qv, s_acc[0]);
            s_acc[1] = fmaf(k0.y, qv, s_acc[1]);
            s_acc[2] = fmaf(k0.z, qv, s_acc[2]);
            s_acc[3] = fmaf(k0.w, qv, s_acc[3]);
            s_acc[4] = fmaf(k1.x, qv, s_acc[4]);
            s_acc[5] = fmaf(k1.y, qv, s_acc[5]);
            s_acc[6] = fmaf(k1.z, qv, s_acc[6]);
            s_acc[7] = fmaf(k1.w, qv, s_acc[7]);
        }

        // ================= online softmax bookkeeping =================
        float tmax = fmaxf(fmaxf(fmaxf(s_acc[0], s_acc[1]), fmaxf(s_acc[2], s_acc[3])),
                           fmaxf(fmaxf(s_acc[4], s_acc[5]), fmaxf(s_acc[6], s_acc[7])));
        red_max[g][j] = tmax;
        __syncthreads();                      // bar1
        float bmax = red_max[0][j];
        #pragma unroll
        for (int gg = 1; gg < 8; ++gg) bmax = fmaxf(bmax, red_max[gg][j]);
        float new_m = fmaxf(m_run, bmax);
        float scale = __expf(m_run - new_m);  // 0 on first block (m_run = -inf)

        float psum = 0.0f;
        float pv[8];
        #pragma unroll
        for (int r = 0; r < 8; ++r) {
            pv[r] = __expf(s_acc[r] - new_m);
            psum += pv[r];
        }
        #pragma unroll
        for (int r = 0; r < 8; ++r) p_t[j][g * 8 + r] = pv[r];
        red_sum[g][j] = psum;
        __syncthreads();                      // bar2

        float bsum = 0.0f;
        #pragma unroll
        for (int gg = 0; gg < 8; ++gg) bsum += red_sum[gg][j];
        l_run = l_run * scale + bsum;
        m_run = new_m;

        #pragma unroll
        for (int x = 0; x < 64; ++x) acc[x] *= scale;

        // ================= Phase B: acc += V_block * P =================
        // acc[cc] += sum_ii V[g*64+cc][i0+ii] * p_t[j][ii]
        const float* vp = Vb + (size_t)(g * 64) * NN + i0;
        for (int i4 = 0; i4 < 16; ++i4) {
            const float4 p4 = *(const float4*)&p_t[j][i4 * 4];
            const float* vpi = vp + i4 * 4;
            #pragma unroll
            for (int cq = 0; cq < 4; ++cq) {
                #pragma unroll
                for (int ci = 0; ci < 16; ++ci) {
                    const int cc = cq * 16 + ci;
                    const float4 vv = *(const float4*)(vpi + (size_t)cc * NN);
                    acc[cc] = fmaf(vv.x, p4.x, acc[cc]);
                    acc[cc] = fmaf(vv.y, p4.y, acc[cc]);
                    acc[cc] = fmaf(vv.z, p4.z, acc[cc]);
                    acc[cc] = fmaf(vv.w, p4.w, acc[cc]);
                }
                // cap in-flight loads (~16 float4) to control VGPR pressure
                asm volatile("" ::: "memory");
            }
        }
    }

    // ================= epilogue: out = q + acc / l =================
    const float inv_l = 1.0f / l_run;
    #pragma unroll
    for (int cc = 0; cc < 64; ++cc) {
        const int c = g * 64 + cc;
        Ob[(size_t)c * NN + j] = q_lds[c][j] + acc[cc] * inv_l;
    }
}

extern "C" void kernel_launch(void* const* d_in, const int* in_sizes, int n_in,
                              void* d_out, int out_size, void* d_ws, size_t ws_size,
                              hipStream_t stream) {
    const float* Q = (const float*)d_in[0];
    const float* K = (const float*)d_in[1];
    const float* V = (const float*)d_in[2];
    float* O = (float*)d_out;

    const int batches = in_sizes[0] / (CC * NN);   // 4
    dim3 grid(batches * NJT);
    dim3 block(TPB);
    hipLaunchKernelGGL(attn_fused_f32, grid, block, 0, stream, Q, K, V, O);
}

// Round 2
// 535.053 us; speedup vs baseline: 16.7602x; 16.7602x over previous
//
#include <hip/hip_runtime.h>
#include <math.h>

typedef __attribute__((ext_vector_type(4))) float f32x4;
typedef __attribute__((ext_vector_type(8))) short bf16x8;

namespace {
constexpr int B_ = 4, C_ = 512, N_ = 4096;
constexpr int JT  = 64;            // query columns per WG
constexpr int IB  = 128;           // key rows per flash iteration
constexpr int KC  = 32;            // channel chunk staged in LDS
constexpr int NCH = C_ / KC;       // 16
constexpr int NIB = N_ / IB;       // 32
constexpr int PITCH = 40;          // ushorts per LDS row (80 B = 5*16, conflict-free)
}

__device__ __forceinline__ unsigned short f2bf(float f) {
    unsigned int u = __float_as_uint(f);
    u = (u + 0x7fffu + ((u >> 16) & 1u)) >> 16;
    return (unsigned short)u;
}
__device__ __forceinline__ float bf2f(unsigned short h) {
    return __uint_as_float(((unsigned int)h) << 16);
}

// ---------- pre-pass 1: X[b][c][i] (f32) -> Xt hi/lo [b][i][c] (bf16 split) ----------
__global__ __launch_bounds__(256)
void cvt_transpose_split(const float* __restrict__ X,
                         unsigned short* __restrict__ Xh,
                         unsigned short* __restrict__ Xl)
{
    __shared__ float tile[64][66];
    const int t   = (int)threadIdx.x;
    const int blk = (int)blockIdx.x;
    const int b   = blk >> 9;            // 512 tiles per batch
    const int r   = blk & 511;
    const int it  = r >> 3;              // i-tile of 64 (0..63)
    const int ct  = r & 7;               // c-tile of 64 (0..7)

    const float* src = X + ((size_t)(b * C_ + ct * 64)) * N_ + it * 64;
    #pragma unroll
    for (int rep = 0; rep < 4; ++rep) {
        int idx = rep * 256 + t;
        int c   = idx >> 4;              // 0..63
        int i4  = (idx & 15) * 4;
        const float4 v = *(const float4*)(src + (size_t)c * N_ + i4);
        tile[c][i4 + 0] = v.x; tile[c][i4 + 1] = v.y;
        tile[c][i4 + 2] = v.z; tile[c][i4 + 3] = v.w;
    }
    __syncthreads();
    unsigned short* dh = Xh + ((size_t)(b * N_ + it * 64)) * C_ + ct * 64;
    unsigned short* dl = Xl + ((size_t)(b * N_ + it * 64)) * C_ + ct * 64;
    #pragma unroll
    for (int rep = 0; rep < 4; ++rep) {
        int idx = rep * 256 + t;
        int i   = idx >> 4;              // 0..63
        int c4  = (idx & 15) * 4;
        ushort4 hv, lv;
        {
            float f0 = tile[c4 + 0][i], f1 = tile[c4 + 1][i];
            float f2 = tile[c4 + 2][i], f3 = tile[c4 + 3][i];
            hv.x = f2bf(f0); lv.x = f2bf(f0 - bf2f(hv.x));
            hv.y = f2bf(f1); lv.y = f2bf(f1 - bf2f(hv.y));
            hv.z = f2bf(f2); lv.z = f2bf(f2 - bf2f(hv.z));
            hv.w = f2bf(f3); lv.w = f2bf(f3 - bf2f(hv.w));
        }
        *(ushort4*)(dh + (size_t)i * C_ + c4) = hv;
        *(ushort4*)(dl + (size_t)i * C_ + c4) = lv;
    }
}

// ---------- pre-pass 2: V (f32) -> V hi (bf16), same [b][c][i] layout ----------
__global__ __launch_bounds__(256)
void cvt_split_hi(const float* __restrict__ X, unsigned short* __restrict__ Xh)
{
    size_t base = ((size_t)blockIdx.x * 256 + threadIdx.x) * 16;
    #pragma unroll
    for (int g = 0; g < 2; ++g) {
        float4 a = *(const float4*)(X + base + g * 8);
        float4 c = *(const float4*)(X + base + g * 8 + 4);
        ushort4 h0, h1;
        h0.x = f2bf(a.x); h0.y = f2bf(a.y); h0.z = f2bf(a.z); h0.w = f2bf(a.w);
        h1.x = f2bf(c.x); h1.y = f2bf(c.y); h1.z = f2bf(c.z); h1.w = f2bf(c.w);
        *(ushort4*)(Xh + base + g * 8)     = h0;
        *(ushort4*)(Xh + base + g * 8 + 4) = h1;
    }
}

// ---------- main fused flash-attention kernel (MFMA, split-bf16 QK^T) ----------
__global__ __launch_bounds__(512, 2)
void attn_mfma(const unsigned short* __restrict__ Kth,
               const unsigned short* __restrict__ Ktl,
               const unsigned short* __restrict__ Qth,
               const unsigned short* __restrict__ Qtl,
               const unsigned short* __restrict__ Vh,
               const float* __restrict__ Qorig,
               float* __restrict__ Out)
{
    __shared__ unsigned short Kh[2][IB][PITCH];
    __shared__ unsigned short Kl[2][IB][PITCH];
    __shared__ unsigned short Qh[2][JT][PITCH];
    __shared__ unsigned short Ql[2][JT][PITCH];
    __shared__ unsigned short Pt[JT * IB];     // XOR-swizzled [j][i] bf16
    __shared__ float m_lds[JT], l_lds[JT], scale_lds[JT];
    __shared__ float red_max[4][JT], red_sum[4][JT];

    const int t    = (int)threadIdx.x;
    const int w    = t >> 6;
    const int lane = t & 63;
    const int lr   = lane & 15;
    const int lg   = lane >> 4;
    const int iw   = w & 3;                    // i-subrange owner (phase A)
    const int jh   = w >> 2;                   // j-half owner (phase A)

    // XCD-aware swizzle: 32 consecutive logical WGs (same batch) per XCD
    const int bidl = ((int)blockIdx.x & 7) * 32 + ((int)blockIdx.x >> 3);
    const int b    = bidl >> 6;
    const int j0   = (bidl & 63) * JT;

    // staging decomposition
    const int ist  = t >> 2;                   // 0..127  (K rows)
    const int cst  = (t & 3) * 8;              // 0,8,16,24
    const int jst  = t >> 3;                   // 0..63   (Q rows)
    const int cqst = (t & 7) * 4;              // 0..28

    if (t < JT) { m_lds[t] = -INFINITY; l_lds[t] = 0.0f; }

    f32x4 Oacc[4][4];
    #pragma unroll
    for (int a = 0; a < 4; ++a)
        #pragma unroll
        for (int c = 0; c < 4; ++c) Oacc[a][c] = (f32x4)0.0f;

    __syncthreads();

    auto stage = [&](int ck, int dbuf) {
        const size_t kbase = ((size_t)(b * N_ + 0) + 0) * C_; // folded below
        const size_t koff  = ((size_t)(b * N_ + (int)0)) * C_;
        (void)kbase; (void)koff;
    };
    (void)stage;

    for (int ib = 0; ib < NIB; ++ib) {
        const int i0 = ib * IB;

        f32x4 Sacc[2][2];
        #pragma unroll
        for (int x = 0; x < 2; ++x)
            #pragma unroll
            for (int y = 0; y < 2; ++y) Sacc[x][y] = (f32x4)0.0f;

        // ---- prologue: stage chunk 0 into buf 0 ----
        {
            const size_t kb = ((size_t)(b * N_ + i0 + ist)) * C_ + cst;
            *(uint4*)&Kh[0][ist][cst] = *(const uint4*)(Kth + kb);
            *(uint4*)&Kl[0][ist][cst] = *(const uint4*)(Ktl + kb);
            const size_t qb = ((size_t)(b * N_ + j0 + jst)) * C_ + cqst;
            *(uint2*)&Qh[0][jst][cqst] = *(const uint2*)(Qth + qb);
            *(uint2*)&Ql[0][jst][cqst] = *(const uint2*)(Qtl + qb);
        }
        __syncthreads();

        // ---- phase A: S = K^T Q over c-chunks (double-buffered, 1 barrier/chunk) ----
        for (int ck = 0; ck < NCH; ++ck) {
            const int d = ck & 1;
            if (ck + 1 < NCH) {
                const int cc = (ck + 1) * KC;
                const size_t kb = ((size_t)(b * N_ + i0 + ist)) * C_ + cc + cst;
                *(uint4*)&Kh[d ^ 1][ist][cst] = *(const uint4*)(Kth + kb);
                *(uint4*)&Kl[d ^ 1][ist][cst] = *(const uint4*)(Ktl + kb);
                const size_t qb = ((size_t)(b * N_ + j0 + jst)) * C_ + cc + cqst;
                *(uint2*)&Qh[d ^ 1][jst][cqst] = *(const uint2*)(Qth + qb);
                *(uint2*)&Ql[d ^ 1][jst][cqst] = *(const uint2*)(Qtl + qb);
            }
            bf16x8 bqh[2], bql[2];
            #pragma unroll
            for (int jt = 0; jt < 2; ++jt) {
                const int j = jh * 32 + jt * 16 + lr;
                bqh[jt] = *(const bf16x8*)&Qh[d][j][lg * 8];
                bql[jt] = *(const bf16x8*)&Ql[d][j][lg * 8];
            }
            #pragma unroll
            for (int it = 0; it < 2; ++it) {
                const int i = iw * 32 + it * 16 + lr;
                const bf16x8 akh = *(const bf16x8*)&Kh[d][i][lg * 8];
                const bf16x8 akl = *(const bf16x8*)&Kl[d][i][lg * 8];
                #pragma unroll
                for (int jt = 0; jt < 2; ++jt) {
                    Sacc[it][jt] = __builtin_amdgcn_mfma_f32_16x16x32_bf16(akh, bqh[jt], Sacc[it][jt], 0, 0, 0);
                    Sacc[it][jt] = __builtin_amdgcn_mfma_f32_16x16x32_bf16(akh, bql[jt], Sacc[it][jt], 0, 0, 0);
                    Sacc[it][jt] = __builtin_amdgcn_mfma_f32_16x16x32_bf16(akl, bqh[jt], Sacc[it][jt], 0, 0, 0);
                }
            }
            __syncthreads();
        }

        // ---- (a) per-column block max ----
        #pragma unroll
        for (int jt = 0; jt < 2; ++jt) {
            float mx = -INFINITY;
            #pragma unroll
            for (int it = 0; it < 2; ++it)
                #pragma unroll
                for (int r = 0; r < 4; ++r) mx = fmaxf(mx, Sacc[it][jt][r]);
            mx = fmaxf(mx, __shfl_xor(mx, 16));
            mx = fmaxf(mx, __shfl_xor(mx, 32));
            if (lane < 16) red_max[iw][jh * 32 + jt * 16 + lane] = mx;
        }
        __syncthreads();

        // ---- (b) running max + rescale factor ----
        if (t < JT) {
            const float m_old = m_lds[t];
            float bm = fmaxf(fmaxf(red_max[0][t], red_max[1][t]),
                             fmaxf(red_max[2][t], red_max[3][t]));
            const float m_new = fmaxf(m_old, bm);
            m_lds[t] = m_new;
            scale_lds[t] = __expf(m_old - m_new);
        }
        __syncthreads();

        // ---- (c) exp, P -> LDS (swizzled), column partial sums, O-rescale ----
        #pragma unroll
        for (int jt = 0; jt < 2; ++jt) {
            const int j = jh * 32 + jt * 16 + lr;
            const float mcol = m_lds[j];
            float csum = 0.0f;
            #pragma unroll
            for (int it = 0; it < 2; ++it) {
                const float p0 = __expf(Sacc[it][jt][0] - mcol);
                const float p1 = __expf(Sacc[it][jt][1] - mcol);
                const float p2 = __expf(Sacc[it][jt][2] - mcol);
                const float p3 = __expf(Sacc[it][jt][3] - mcol);
                csum += (p0 + p1) + (p2 + p3);
                ushort4 pk;
                pk.x = f2bf(p0); pk.y = f2bf(p1); pk.z = f2bf(p2); pk.w = f2bf(p3);
                const int i = iw * 32 + it * 16 + lg * 4;
                const unsigned byteoff =
                    ((unsigned)(j * (IB * 2) + i * 2)) ^ (((unsigned)(j & 7)) << 4);
                *(ushort4*)((char*)Pt + byteoff) = pk;
            }
            csum += __shfl_xor(csum, 16);
            csum += __shfl_xor(csum, 32);
            if (lane < 16) red_sum[iw][j] = csum;
        }
        {
            float scj[4];
            #pragma unroll
            for (int jt = 0; jt < 4; ++jt) scj[jt] = scale_lds[jt * 16 + lr];
            #pragma unroll
            for (int ct = 0; ct < 4; ++ct)
                #pragma unroll
                for (int jt = 0; jt < 4; ++jt) {
                    Oacc[ct][jt][0] *= scj[jt];
                    Oacc[ct][jt][1] *= scj[jt];
                    Oacc[ct][jt][2] *= scj[jt];
                    Oacc[ct][jt][3] *= scj[jt];
                }
        }
        __syncthreads();

        // ---- (d) running denominator (parallel with phase B) ----
        if (t < JT)
            l_lds[t] = l_lds[t] * scale_lds[t] +
                       (red_sum[0][t] + red_sum[1][t]) + (red_sum[2][t] + red_sum[3][t]);

        // ---- phase B: Oacc += V_block * P ----
        {
            const int c0w = w * 64;
            #pragma unroll
            for (int ks = 0; ks < 4; ++ks) {
                bf16x8 pf[4];
                #pragma unroll
                for (int jt = 0; jt < 4; ++jt) {
                    const int j = jt * 16 + lr;
                    const unsigned byteoff =
                        ((unsigned)(j * (IB * 2) + ks * 64 + lg * 16)) ^ (((unsigned)(j & 7)) << 4);
                    pf[jt] = *(const bf16x8*)((char*)Pt + byteoff);
                }
                #pragma unroll
                for (int ct = 0; ct < 4; ++ct) {
                    const int c = c0w + ct * 16 + lr;
                    const bf16x8 vf =
                        *(const bf16x8*)(Vh + ((size_t)(b * C_ + c)) * N_ + i0 + ks * 32 + lg * 8);
                    #pragma unroll
                    for (int jt = 0; jt < 4; ++jt)
                        Oacc[ct][jt] = __builtin_amdgcn_mfma_f32_16x16x32_bf16(vf, pf[jt], Oacc[ct][jt], 0, 0, 0);
                }
            }
        }
        // no barrier needed here: next write to Pt/red/* is >=2 barriers away
    }

    __syncthreads();   // final l_lds visible

    // ---- epilogue: out = q + Oacc / l ----
    {
        float il[4];
        #pragma unroll
        for (int jt = 0; jt < 4; ++jt) il[jt] = 1.0f / l_lds[jt * 16 + lr];
        const int c0w = w * 64;
        #pragma unroll
        for (int ct = 0; ct < 4; ++ct) {
            #pragma unroll
            for (int r = 0; r < 4; ++r) {
                const int c = c0w + ct * 16 + lg * 4 + r;
                const float* qrow = Qorig + ((size_t)(b * C_ + c)) * N_ + j0;
                float*       orow = Out   + ((size_t)(b * C_ + c)) * N_ + j0;
                #pragma unroll
                for (int jt = 0; jt < 4; ++jt) {
                    const int j = jt * 16 + lr;
                    orow[j] = qrow[j] + Oacc[ct][jt][r] * il[jt];
                }
            }
        }
    }
}

// ---------- fallback (round-1 f32 kernel) if workspace is too small ----------
namespace {
constexpr int FJT = 32, FIB = 64, FTPB = 256, FNJT = N_ / FJT;
}
__global__ __launch_bounds__(FTPB, 2)
void attn_fused_f32(const float* __restrict__ Q,
                    const float* __restrict__ K,
                    const float* __restrict__ V,
                    float* __restrict__ O)
{
    __shared__ float q_lds[C_][FJT];
    __shared__ float p_t[FJT][FIB + 4];
    __shared__ float red_max[8][FJT];
    __shared__ float red_sum[8][FJT];

    const int t  = (int)threadIdx.x;
    const int j  = t & (FJT - 1);
    const int g  = t >> 5;
    const int b  = (int)blockIdx.x / FNJT;
    const int j0 = ((int)blockIdx.x % FNJT) * FJT;

    const float* Qb = Q + ((size_t)b * C_) * N_ + j0;
    const float* Kb = K + ((size_t)b * C_) * N_;
    const float* Vb = V + ((size_t)b * C_) * N_;
    float*       Ob = O + ((size_t)b * C_) * N_ + j0;

    #pragma unroll 4
    for (int r = 0; r < (C_ * FJT) / FTPB; ++r) {
        int idx = r * FTPB + t;
        q_lds[idx >> 5][idx & (FJT - 1)] = Qb[(size_t)(idx >> 5) * N_ + (idx & (FJT - 1))];
    }
    __syncthreads();

    float acc[64];
    #pragma unroll
    for (int x = 0; x < 64; ++x) acc[x] = 0.0f;
    float m_run = -INFINITY, l_run = 0.0f;

    for (int i0 = 0; i0 < N_; i0 += FIB) {
        float s_acc[8];
        #pragma unroll
        for (int r = 0; r < 8; ++r) s_acc[r] = 0.0f;
        const float* kp = Kb + i0 + g * 8;
        #pragma unroll 4
        for (int c = 0; c < C_; ++c) {
            float qv = q_lds[c][j];
            const float4 k0 = *(const float4*)(kp + (size_t)c * N_);
            const float4 k1 = *(const float4*)(kp + (size_t)c * N_ + 4);
            s_acc[0] = fmaf(k0.x, qv, s_acc[0]); s_acc[1] = fmaf(k0.y, qv, s_acc[1]);
            s_acc[2] = fmaf(k0.z, qv, s_acc[2]); s_acc[3] = fmaf(k0.w, qv, s_acc[3]);
            s_acc[4] = fmaf(k1.x, qv, s_acc[4]); s_acc[5] = fmaf(k1.y, qv, s_acc[5]);
            s_acc[6] = fmaf(k1.z, qv, s_acc[6]); s_acc[7] = fmaf(k1.w, qv, s_acc[7]);
        }
        float tmax = fmaxf(fmaxf(fmaxf(s_acc[0], s_acc[1]), fmaxf(s_acc[2], s_acc[3])),
                           fmaxf(fmaxf(s_acc[4], s_acc[5]), fmaxf(s_acc[6], s_acc[7])));
        red_max[g][j] = tmax;
        __syncthreads();
        float bmax = red_max[0][j];
        #pragma unroll
        for (int gg = 1; gg < 8; ++gg) bmax = fmaxf(bmax, red_max[gg][j]);
        float new_m = fmaxf(m_run, bmax);
        float scale = __expf(m_run - new_m);
        float psum = 0.0f, pv[8];
        #pragma unroll
        for (int r = 0; r < 8; ++r) { pv[r] = __expf(s_acc[r] - new_m); psum += pv[r]; }
        #pragma unroll
        for (int r = 0; r < 8; ++r) p_t[j][g * 8 + r] = pv[r];
        red_sum[g][j] = psum;
        __syncthreads();
        float bsum = 0.0f;
        #pragma unroll
        for (int gg = 0; gg < 8; ++gg) bsum += red_sum[gg][j];
        l_run = l_run * scale + bsum;
        m_run = new_m;
        #pragma unroll
        for (int x = 0; x < 64; ++x) acc[x] *= scale;
        const float* vp = Vb + (size_t)(g * 64) * N_ + i0;
        for (int i4 = 0; i4 < 16; ++i4) {
            const float4 p4 = *(const float4*)&p_t[j][i4 * 4];
            const float* vpi = vp + i4 * 4;
            #pragma unroll
            for (int cq = 0; cq < 4; ++cq) {
                #pragma unroll
                for (int ci = 0; ci < 16; ++ci) {
                    const int cc = cq * 16 + ci;
                    const float4 vv = *(const float4*)(vpi + (size_t)cc * N_);
                    acc[cc] = fmaf(vv.x, p4.x, acc[cc]);
                    acc[cc] = fmaf(vv.y, p4.y, acc[cc]);
                    acc[cc] = fmaf(vv.z, p4.z, acc[cc]);
                    acc[cc] = fmaf(vv.w, p4.w, acc[cc]);
                }
                asm volatile("" ::: "memory");
            }
        }
    }
    const float inv_l = 1.0f / l_run;
    #pragma unroll
    for (int cc = 0; cc < 64; ++cc) {
        const int c = g * 64 + cc;
        Ob[(size_t)c * N_ + j] = q_lds[c][j] + acc[cc] * inv_l;
    }
}

extern "C" void kernel_launch(void* const* d_in, const int* in_sizes, int n_in,
                              void* d_out, int out_size, void* d_ws, size_t ws_size,
                              hipStream_t stream) {
    const float* Q = (const float*)d_in[0];
    const float* K = (const float*)d_in[1];
    const float* V = (const float*)d_in[2];
    float* O = (float*)d_out;

    const size_t EL   = (size_t)B_ * C_ * N_;          // 8388608 elements
    const size_t NEED = EL * 2 * 5;                    // 5 bf16 arrays = 80 MiB

    if (ws_size >= NEED) {
        unsigned short* Kth = (unsigned short*)d_ws;
        unsigned short* Ktl = Kth + EL;
        unsigned short* Qth = Ktl + EL;
        unsigned short* Qtl = Qth + EL;
        unsigned short* Vhh = Qtl + EL;
        cvt_transpose_split<<<dim3(2048), dim3(256), 0, stream>>>(K, Kth, Ktl);
        cvt_transpose_split<<<dim3(2048), dim3(256), 0, stream>>>(Q, Qth, Qtl);
        cvt_split_hi<<<dim3(2048), dim3(256), 0, stream>>>(V, Vhh);
        attn_mfma<<<dim3(256), dim3(512), 0, stream>>>(Kth, Ktl, Qth, Qtl, Vhh, Q, O);
    } else {
        attn_fused_f32<<<dim3(B_ * FNJT), dim3(FTPB), 0, stream>>>(Q, K, V, O);
    }
}